// Round 5
// baseline (584.933 us; speedup 1.0000x reference)
//
#include <hip/hip_runtime.h>

typedef unsigned short u16;
typedef __attribute__((ext_vector_type(8))) _Float16 hfrag8;  // 8 f16 = 4 VGPRs (MFMA A/B frag)
typedef __attribute__((ext_vector_type(4))) float f32x4;      // MFMA C/D frag
typedef __attribute__((ext_vector_type(2))) __fp16 fp16x2;    // cvt_pkrtz return type

__device__ __forceinline__ float bu2f(u16 u) { return __uint_as_float(((unsigned)u) << 16); }
__device__ __forceinline__ u16 f2bu(float f) {
    unsigned x = __float_as_uint(f);
    return (u16)((x + 0x7fffu + ((x >> 16) & 1u)) >> 16);   // RNE f32->bf16
}
__device__ __forceinline__ u16 f2hu(float f) {              // f32 -> f16 bit pattern
    _Float16 h = (_Float16)f;
    return __builtin_bit_cast(u16, h);
}
__device__ __forceinline__ unsigned pk2h(float a, float b) { // packed f32x2 -> f16x2
    fp16x2 h = __builtin_amdgcn_cvt_pkrtz(a, b);
    return __builtin_bit_cast(unsigned, h);
}
__device__ __forceinline__ float ldf(const void* p, int i, bool f32) {
    return f32 ? ((const float*)p)[i] : bu2f(((const u16*)p)[i]);
}
__device__ __forceinline__ float siluf(float x) { return x / (1.0f + __expf(-x)); }

// dtype detect, per-block (threads 0..63 sample even u16s of node_features).
// bf16 data: exponents cluster ~[112,130]; f32 mantissa-low words: uniform.
__device__ __forceinline__ bool detect_f32(const void* nf, int* flagS) {
    const int t = threadIdx.x;
    if (t < 64) {
        const u16* p = (const u16*)nf;
        int ext = 0;
        for (int s = 0; s < 4; s++) {
            u16 v = p[(t * 4 + s) * 2];
            int e = (v >> 7) & 0xFF;
            ext += (e >= 140 || e == 0) ? 1 : 0;
        }
#pragma unroll
        for (int d = 1; d < 64; d <<= 1) ext += __shfl_xor(ext, d);
        if (t == 0) *flagS = (ext > 32) ? 1 : 0;
    }
    __syncthreads();
    return *flagS != 0;
}

// ---------------------------------------------------------------------------
// PRE: fused precompute. blocks [0,256): per-node rows; [256,767): T table;
// [767,895): weight transposes.
//   cbar[b,i,:] = mean_a coords ; pi2 = fi@We1[0:128]+cbar_i@We1[384:]+be1
//   qd = fj@We1[128:256]-cbar_j@We1[384:] ; T[d+255] = pe(d)@We1[256:384]
//   We2T/Wc1T: 256x256 -> n-major k-contiguous f16
// ---------------------------------------------------------------------------
__global__ __launch_bounds__(256) void pre_kernel(
    const void* __restrict__ coords, const void* __restrict__ nf,
    const void* __restrict__ We1, const void* __restrict__ be1,
    const void* __restrict__ We2, const void* __restrict__ Wc1,
    float* __restrict__ cbar, float* __restrict__ pi2, float* __restrict__ qd,
    float* __restrict__ Ttab, u16* __restrict__ We2T, u16* __restrict__ Wc1T)
{
    __shared__ int flagS;
    __shared__ float nf_l[4][128];
    __shared__ float ctmp[4][12];
    __shared__ float cb_l[4][3];
    __shared__ float pe[128];
    __shared__ u16 tile[32][33];
    const bool f32 = detect_f32(nf, &flagS);
    const int t = threadIdx.x;
    const int bid = blockIdx.x;

    if (bid < 256) {
        // ---- per-node rows: 4 rows per block ----
        const int row0 = bid * 4;
        for (int idx = t; idx < 512; idx += 256) {
            int r = idx >> 7, k = idx & 127;
            nf_l[r][k] = ldf(nf, (row0 + r) * 128 + k, f32);
        }
        if (t < 48) ctmp[t / 12][t % 12] = ldf(coords, row0 * 12 + t, f32);
        __syncthreads();
        if (t < 12) {
            int r = t / 3, x = t % 3;
            float m = 0.25f * (ctmp[r][x] + ctmp[r][3 + x] + ctmp[r][6 + x] + ctmp[r][9 + x]);
            cb_l[r][x] = m;
            cbar[(row0 + r) * 3 + x] = m;
        }
        __syncthreads();
        const int n = t;
        float accP[4] = {0.f, 0.f, 0.f, 0.f}, accQ[4] = {0.f, 0.f, 0.f, 0.f};
        for (int k = 0; k < 128; k++) {
            float w1 = ldf(We1, k * 256 + n, f32);
            float w2 = ldf(We1, (128 + k) * 256 + n, f32);
#pragma unroll
            for (int r = 0; r < 4; r++) {
                accP[r] += nf_l[r][k] * w1;
                accQ[r] += nf_l[r][k] * w2;
            }
        }
        float wx = ldf(We1, 384 * 256 + n, f32);
        float wy = ldf(We1, 385 * 256 + n, f32);
        float wz = ldf(We1, 386 * 256 + n, f32);
        float b1 = ldf(be1, n, f32);
#pragma unroll
        for (int r = 0; r < 4; r++) {
            float d = cb_l[r][0] * wx + cb_l[r][1] * wy + cb_l[r][2] * wz;
            pi2[(row0 + r) * 256 + n] = accP[r] + d + b1;
            qd[(row0 + r) * 256 + n]  = accQ[r] - d;
        }
    } else if (bid < 767) {
        // ---- T table: one d per block, d = bid-511 in [-255,255] ----
        const float d = (float)(bid - 511);
        if (t < 64) {
            float ang = d * 3.14159265358979323846f * exp2f(-(float)t * 0.125f);
            pe[t] = sinf(ang);
            pe[64 + t] = cosf(ang);
        }
        __syncthreads();
        float acc = 0.f;
        for (int k = 0; k < 128; k++) acc += pe[k] * ldf(We1, (256 + k) * 256 + t, f32);
        Ttab[(bid - 256) * 256 + t] = acc;
    } else {
        // ---- weight transpose -> f16 ----
        const int tb2 = bid - 767;
        const int mat = tb2 >> 6;
        const int tb = tb2 & 63;
        const int bx = tb & 7, by = tb >> 3;
        const void* src = mat ? Wc1 : We2;
        u16* dst = mat ? Wc1T : We2T;
        int tx = t & 31, ty = t >> 5;
#pragma unroll
        for (int p = 0; p < 4; p++) {
            int r = by * 32 + ty + p * 8;
            tile[ty + p * 8][tx] = f2hu(ldf(src, r * 256 + bx * 32 + tx, f32));
        }
        __syncthreads();
#pragma unroll
        for (int p = 0; p < 4; p++) {
            int r = bx * 32 + ty + p * 8;
            dst[r * 256 + by * 32 + tx] = tile[tx][ty + p * 8];
        }
    }
}

// ---------------------------------------------------------------------------
// EDGE: one WG per (b,i); j in 4 chunks of 64. Single S buffer (h1 then msg).
// Transposed GEMM form: D[n][j] = W^T x h^T so epilogue stores are packed
// (lane's 4 acc rows = 4 consecutive cols of msg) and phase-3 reads msg
// as B-fragments straight from [row][k-contig] layout.
// ---------------------------------------------------------------------------
__global__ __launch_bounds__(256, 4) void edge_kernel(
    const int* __restrict__ resid,
    const float* __restrict__ pi2, const float* __restrict__ qd,
    const float* __restrict__ Ttab, const float* __restrict__ cbar,
    const u16* __restrict__ We2T, const u16* __restrict__ Wc1T,
    const void* __restrict__ be2, const void* __restrict__ bc1,
    const void* __restrict__ Wc2, const void* __restrict__ bc2,
    const void* __restrict__ nf,
    float* __restrict__ agg_out, float* __restrict__ cupd_out)
{
    const int wg = blockIdx.x;            // b*256 + i
    const int b = wg >> 8;
    const int t = threadIdx.x;
    const int lane = t & 63, w = t >> 6;  // wave w owns channels [64w,64w+64)
    const int c = lane & 15, q = lane >> 4;

    __shared__ __align__(16) u16 S[64][264];   // h1 then msg (f16), pitch 528B
    __shared__ float pi2_l[256], be2_l[256], bc1_l[256], wc2_l[256], agg_l[256];
    __shared__ u16 relidx[256];
    __shared__ float cupart[4][64];
    __shared__ float cacc[4];
    __shared__ float cbi[3];
    __shared__ int flagS;

    const bool f32 = detect_f32(nf, &flagS);

    int ri = resid[(b << 8) + (wg & 255)];
    relidx[t] = (u16)(ri - resid[(b << 8) + t] + 255);
    pi2_l[t] = pi2[wg * 256 + t];
    be2_l[t] = ldf(be2, t, f32);
    bc1_l[t] = ldf(bc1, t, f32);
    wc2_l[t] = ldf(Wc2, t, f32);
    agg_l[t] = 0.f;
    if (t < 4) cacc[t] = 0.f;
    if (t < 3) cbi[t] = cbar[wg * 3 + t];
    const float bc2v = ldf(bc2, 0, f32);
    __syncthreads();

    const f32x4 zf = {0.f, 0.f, 0.f, 0.f};
    for (int jc = 0; jc < 4; jc++) {
        const int j0 = jc << 6;
        // ---- phase 1: h1 = silu(pi2[i] + qd[j] + T[rel]) -> S (f16) ----
        {
            const int k = (t & 127) << 1;
            const int jh = t >> 7;
            const float p0 = pi2_l[k], p1 = pi2_l[k + 1];
            for (int jj = jh * 32; jj < jh * 32 + 32; jj++) {
                const int j = j0 + jj;
                const float2 qv = *(const float2*)(qd + ((b << 8) + j) * 256 + k);
                const float2 tv = *(const float2*)(Ttab + (int)relidx[j] * 256 + k);
                *(unsigned*)&S[jj][k] = pk2h(siluf(p0 + qv.x + tv.x), siluf(p1 + qv.y + tv.y));
            }
        }
        __syncthreads();

        // ---- phase 2 MFMA: D2[nchan][jrow], A=We2T frag, B=h1 frag ----
        f32x4 acc[4][4];
#pragma unroll
        for (int nt = 0; nt < 4; nt++)
#pragma unroll
            for (int mt = 0; mt < 4; mt++) acc[nt][mt] = zf;
#pragma unroll
        for (int ks = 0; ks < 8; ks++) {
            const int kb = ks * 32 + q * 8;
            hfrag8 aw[4], bh[4];
#pragma unroll
            for (int nt = 0; nt < 4; nt++)
                aw[nt] = *(const hfrag8*)(We2T + (w * 64 + nt * 16 + c) * 256 + kb);
#pragma unroll
            for (int mt = 0; mt < 4; mt++) bh[mt] = *(const hfrag8*)&S[mt * 16 + c][kb];
#pragma unroll
            for (int nt = 0; nt < 4; nt++)
#pragma unroll
                for (int mt = 0; mt < 4; mt++)
                    acc[nt][mt] = __builtin_amdgcn_mfma_f32_16x16x32_f16(aw[nt], bh[mt], acc[nt][mt], 0, 0, 0);
        }
        __syncthreads();   // all h1 reads complete before S is overwritten

        // ---- phase 2 epilogue: msg = silu(+be2) -> S packed b64; agg ----
#pragma unroll
        for (int nt = 0; nt < 4; nt++) {
            const int nb = w * 64 + nt * 16 + q * 4;
            const float4 bias = *(const float4*)&be2_l[nb];
            float sm[4] = {0.f, 0.f, 0.f, 0.f};
#pragma unroll
            for (int mt = 0; mt < 4; mt++) {
                float s0 = siluf(acc[nt][mt][0] + bias.x);
                float s1 = siluf(acc[nt][mt][1] + bias.y);
                float s2 = siluf(acc[nt][mt][2] + bias.z);
                float s3 = siluf(acc[nt][mt][3] + bias.w);
                sm[0] += s0; sm[1] += s1; sm[2] += s2; sm[3] += s3;
                uint2 pk;
                pk.x = pk2h(s0, s1);
                pk.y = pk2h(s2, s3);
                *(uint2*)&S[mt * 16 + c][nb] = pk;
            }
#pragma unroll
            for (int r = 0; r < 4; r++) {
                float v = sm[r];
                v += __shfl_xor(v, 1); v += __shfl_xor(v, 2);
                v += __shfl_xor(v, 4); v += __shfl_xor(v, 8);
                if (c == 0) agg_l[nb + r] += v;   // waves own disjoint channels
            }
        }
        __syncthreads();

        // ---- phase 3 MFMA: D3[p][jrow], A=Wc1T frag, B=msg frag ----
#pragma unroll
        for (int pt = 0; pt < 4; pt++)
#pragma unroll
            for (int mt = 0; mt < 4; mt++) acc[pt][mt] = zf;
#pragma unroll
        for (int ks = 0; ks < 8; ks++) {
            const int kb = ks * 32 + q * 8;
            hfrag8 aw[4], bm[4];
#pragma unroll
            for (int pt = 0; pt < 4; pt++)
                aw[pt] = *(const hfrag8*)(Wc1T + (w * 64 + pt * 16 + c) * 256 + kb);
#pragma unroll
            for (int mt = 0; mt < 4; mt++) bm[mt] = *(const hfrag8*)&S[mt * 16 + c][kb];
#pragma unroll
            for (int pt = 0; pt < 4; pt++)
#pragma unroll
                for (int mt = 0; mt < 4; mt++)
                    acc[pt][mt] = __builtin_amdgcn_mfma_f32_16x16x32_f16(aw[pt], bm[mt], acc[pt][mt], 0, 0, 0);
        }
        // ---- phase 3 epilogue: cu row-dot with Wc2 ----
        float dotv[4] = {0.f, 0.f, 0.f, 0.f};
#pragma unroll
        for (int pt = 0; pt < 4; pt++) {
            const int pb = w * 64 + pt * 16 + q * 4;
            const float4 bias = *(const float4*)&bc1_l[pb];
            const float4 wv = *(const float4*)&wc2_l[pb];
#pragma unroll
            for (int mt = 0; mt < 4; mt++) {
                dotv[mt] += siluf(acc[pt][mt][0] + bias.x) * wv.x
                          + siluf(acc[pt][mt][1] + bias.y) * wv.y
                          + siluf(acc[pt][mt][2] + bias.z) * wv.z
                          + siluf(acc[pt][mt][3] + bias.w) * wv.w;
            }
        }
#pragma unroll
        for (int mt = 0; mt < 4; mt++) {
            float v = dotv[mt];
            v += __shfl_xor(v, 16); v += __shfl_xor(v, 32);
            if (q == 0) cupart[w][mt * 16 + c] = v;
        }
        __syncthreads();
        if (w == 0) {                          // cross-wave cu + coord accum
            const int j = j0 + lane;
            float cu = cupart[0][lane] + cupart[1][lane] + cupart[2][lane] + cupart[3][lane] + bc2v;
            const float cx = cbar[((b << 8) + j) * 3 + 0];
            const float cy = cbar[((b << 8) + j) * 3 + 1];
            const float cz = cbar[((b << 8) + j) * 3 + 2];
            float s0 = cu, s1 = cu * cx, s2 = cu * cy, s3 = cu * cz;
#pragma unroll
            for (int d = 1; d < 64; d <<= 1) {
                s0 += __shfl_xor(s0, d);
                s1 += __shfl_xor(s1, d);
                s2 += __shfl_xor(s2, d);
                s3 += __shfl_xor(s3, d);
            }
            if (lane == 0) { cacc[0] += s0; cacc[1] += s1; cacc[2] += s2; cacc[3] += s3; }
        }
        __syncthreads();
    }
    agg_out[wg * 256 + t] = agg_l[t];
    if (t == 0) {
        // coord_upd = (sum cu)*cbar_i - sum(cu*cbar_j)
        cupd_out[wg * 3 + 0] = cacc[0] * cbi[0] - cacc[1];
        cupd_out[wg * 3 + 1] = cacc[0] * cbi[1] - cacc[2];
        cupd_out[wg * 3 + 2] = cacc[0] * cbi[2] - cacc[3];
    }
}

// ---------------------------------------------------------------------------
// POST: blocks [0,128): node MLP + LayerNorm (8 rows/block) -> d_out[12288..]
//       blocks [128,176): updated_coords (48 blocks x 256 = 12288 elements)
// ---------------------------------------------------------------------------
__global__ __launch_bounds__(256) void post_kernel(
    const void* __restrict__ nf, const float* __restrict__ agg,
    const void* __restrict__ Wn1, const void* __restrict__ bn1,
    const void* __restrict__ Wn2, const void* __restrict__ bn2,
    const void* __restrict__ gamma, const void* __restrict__ beta,
    const void* __restrict__ coords, const void* __restrict__ mask,
    const float* __restrict__ cupd, void* __restrict__ d_out)
{
    __shared__ int flagS;
    __shared__ float x_l[8][384];
    __shared__ float hs[8][256];
    __shared__ float ho[8][128];
    const bool f32 = detect_f32(nf, &flagS);
    const int t = threadIdx.x;

    if (blockIdx.x >= 128) {
        int idx = (blockIdx.x - 128) * 256 + t;
        if (idx < 4 * 256 * 4 * 3) {
            int x = idx % 3;
            int a = (idx / 3) & 3;
            int node = idx / 12;
            float v = ldf(coords, idx, f32) + cupd[node * 3 + x] * ldf(mask, node * 4 + a, f32);
            if (f32) ((float*)d_out)[idx] = v;
            else     ((u16*)d_out)[idx] = f2bu(v);
        }
        return;
    }

    const int row0 = blockIdx.x * 8;
    for (int idx = t; idx < 8 * 384; idx += 256) {
        int r = idx / 384, k = idx % 384;
        x_l[r][k] = (k < 128) ? ldf(nf, (row0 + r) * 128 + k, f32)
                              : agg[(row0 + r) * 256 + (k - 128)];
    }
    __syncthreads();
    {
        float a1[8] = {0.f, 0.f, 0.f, 0.f, 0.f, 0.f, 0.f, 0.f};
        for (int k = 0; k < 384; k++) {
            float wv = ldf(Wn1, k * 256 + t, f32);
#pragma unroll
            for (int r = 0; r < 8; r++) a1[r] += x_l[r][k] * wv;
        }
        float b1 = ldf(bn1, t, f32);
#pragma unroll
        for (int r = 0; r < 8; r++) hs[r][t] = siluf(a1[r] + b1);
    }
    __syncthreads();
    {
        int cc = t & 127, rg = (t >> 7) * 4;
        float a2[4] = {0.f, 0.f, 0.f, 0.f};
        for (int k = 0; k < 256; k++) {
            float wv = ldf(Wn2, k * 128 + cc, f32);
#pragma unroll
            for (int r = 0; r < 4; r++) a2[r] += hs[rg + r][k] * wv;
        }
        float b2 = ldf(bn2, cc, f32);
#pragma unroll
        for (int r = 0; r < 4; r++) ho[rg + r][cc] = a2[r] + b2;
    }
    __syncthreads();
    {
        int row = t >> 5, s = t & 31;
        float sm = 0.f, sq = 0.f;
#pragma unroll
        for (int u = 0; u < 4; u++) {
            float v = ho[row][s + 32 * u];
            sm += v; sq += v * v;
        }
#pragma unroll
        for (int d = 1; d < 32; d <<= 1) {
            sm += __shfl_xor(sm, d);
            sq += __shfl_xor(sq, d);
        }
        float mu = sm * (1.f / 128.f);
        float var = sq * (1.f / 128.f) - mu * mu;
        float inv = rsqrtf(var + 1e-5f);
#pragma unroll
        for (int u = 0; u < 4; u++) {
            int cc = s + 32 * u;
            float y = (ho[row][cc] - mu) * inv;
            float outv = y * ldf(gamma, cc, f32) + ldf(beta, cc, f32);
            int oi = 12288 + (row0 + row) * 128 + cc;
            if (f32) ((float*)d_out)[oi] = outv;
            else     ((u16*)d_out)[oi] = f2bu(outv);
        }
    }
}

extern "C" void kernel_launch(void* const* d_in, const int* in_sizes, int n_in,
                              void* d_out, int out_size, void* d_ws, size_t ws_size,
                              hipStream_t stream)
{
    const void* coords = d_in[0];
    const void* nf     = d_in[1];
    const void* mask   = d_in[2];
    const int* resid   = (const int*)d_in[3];
    const void* We1 = d_in[4];
    const void* be1 = d_in[5];
    const void* We2 = d_in[6];
    const void* be2 = d_in[7];
    const void* Wn1 = d_in[8];
    const void* bn1 = d_in[9];
    const void* Wn2 = d_in[10];
    const void* bn2 = d_in[11];
    const void* gamma = d_in[12];
    const void* beta  = d_in[13];
    const void* Wc1 = d_in[14];
    const void* bc1 = d_in[15];
    const void* Wc2 = d_in[16];
    const void* bc2 = d_in[17];

    // workspace layout: f32 arrays then f16 transposed weights (~3.96 MB)
    float* f   = (float*)d_ws;
    float* cbar = f;                 // 1024*3
    float* pi2  = cbar + 3072;       // 1024*256
    float* qd   = pi2 + 262144;      // 1024*256
    float* Ttab = qd + 262144;       // 511*256
    float* agg  = Ttab + 130816;     // 1024*256
    float* cupd = agg + 262144;      // 1024*3
    u16* We2T = (u16*)(cupd + 3072); // 256*256 f16
    u16* Wc1T = We2T + 65536;        // 256*256 f16

    hipLaunchKernelGGL(pre_kernel, dim3(895), dim3(256), 0, stream,
                       coords, nf, We1, be1, We2, Wc1, cbar, pi2, qd, Ttab, We2T, Wc1T);
    hipLaunchKernelGGL(edge_kernel, dim3(1024), dim3(256), 0, stream,
                       resid, pi2, qd, Ttab, cbar, We2T, Wc1T, be2, bc1, Wc2, bc2, nf, agg, cupd);
    hipLaunchKernelGGL(post_kernel, dim3(176), dim3(256), 0, stream,
                       nf, agg, Wn1, bn1, Wn2, bn2, gamma, beta, coords, mask, cupd, d_out);
}